// Round 7
// baseline (203.782 us; speedup 1.0000x reference)
//
#include <hip/hip_runtime.h>
#include <stdint.h>

typedef unsigned short u16;
typedef __attribute__((ext_vector_type(8))) short short8;   // 8 bf16 (4 VGPRs) — MFMA A/B frag
typedef __attribute__((ext_vector_type(4))) float float4v;  // MFMA C/D frag

__device__ __forceinline__ u16 f2bf(float f) {
    union { float f; uint32_t u; } v; v.f = f;
    uint32_t r = v.u + 0x7fffu + ((v.u >> 16) & 1u);  // RNE
    return (u16)(r >> 16);
}

__device__ __forceinline__ void gload16(const u16* g, u16* l) {
    __builtin_amdgcn_global_load_lds(
        (const __attribute__((address_space(1))) void*)g,
        (__attribute__((address_space(3))) void*)l, 16, 0, 0);
}

// ---------------- fused prep v2 ----------------
// block ranges: [0,4096) cvt | [4096,4608) merge (wide-read) | [4608,4618) bias
// merge: each block owns a 16(i) x 256(o) patch of one layer's merged W.
// Read: for (e,il): 256 lanes x 4B = 1 KB contiguous (vs 128-B granules in v1).
// Accumulate 16 f32 regs/thread (thread t = column o0+t), LDS-transpose, write
// Wt[(o0+o)*K + i0+i] with 16 lanes contiguous along i (32-B stores; writes are tiny).
// Accumulation order identical to v1 (sum_e wn_e, then *inv, then f2bf).
__global__ __launch_bounds__(256) void prep_fused(
    const float* __restrict__ x, u16* __restrict__ xbf,
    const float* __restrict__ wts,
    const float* __restrict__ W0, const float* __restrict__ W1, const float* __restrict__ W2,
    u16* __restrict__ W0t, u16* __restrict__ W1t, u16* __restrict__ W2t,
    const float* __restrict__ b0, const float* __restrict__ b1, const float* __restrict__ b2,
    float* __restrict__ bm) {
    __shared__ float tile[16][257];   // 16.4 KB, pad -> bank-conflict-free both phases
    const int b = blockIdx.x, tid = threadIdx.x;

    if (b < 4096) {                       // ---- x -> bf16, 4 elem/thread ----
        int i = (b * 256 + tid) * 4;
        float4 v = *(const float4*)(x + i);
        union { u16 s[4]; uint64_t q; } o;
        o.s[0] = f2bf(v.x); o.s[1] = f2bf(v.y); o.s[2] = f2bf(v.z); o.s[3] = f2bf(v.w);
        *(uint64_t*)(xbf + i) = o.q;
        return;
    }

    float wn[8]; float s = 0.f;
    #pragma unroll
    for (int e = 0; e < 8; ++e) { wn[e] = wts[e]; s += wn[e]; }
    const float inv = 1.0f / s;

    if (b < 4608) {                       // ---- weight merge (wide reads) ----
        const float* W; u16* Wt; int K, N, lb;
        if (b < 4224)      { W = W0; Wt = W0t; K = 512;  N = 1024; lb = b - 4096; }  // 128 blocks
        else if (b < 4480) { W = W1; Wt = W1t; K = 1024; N = 1024; lb = b - 4224; }  // 256 blocks
        else               { W = W2; Wt = W2t; K = 1024; N = 512;  lb = b - 4480; }  // 128 blocks
        const int no = N >> 8;                          // 256-wide o-tiles
        const int i0 = (lb / no) * 16, o0 = (lb % no) * 256;

        float acc[16];
        #pragma unroll
        for (int il = 0; il < 16; ++il) acc[il] = 0.f;
        for (int e = 0; e < 8; ++e) {
            const float* base = W + (size_t)e * K * N + (size_t)i0 * N + o0 + tid;
            const float we = wn[e];
            #pragma unroll
            for (int il = 0; il < 16; ++il)
                acc[il] += we * base[(size_t)il * N];   // 1 KB contiguous per (e,il)
        }
        #pragma unroll
        for (int il = 0; il < 16; ++il)
            tile[il][tid] = acc[il] * inv;
        __syncthreads();
        // transposed write: t = g*16+l -> o = rep*16+g, i = l
        const int l = tid & 15, g = tid >> 4;
        #pragma unroll
        for (int rep = 0; rep < 16; ++rep) {
            int o = rep * 16 + g;
            Wt[(size_t)(o0 + o) * K + i0 + l] = f2bf(tile[l][o]);
        }
        return;
    }

    // ---- bias merge: 2560 outputs ----
    int t = (b - 4608) * 256 + tid;
    if (t >= 2560) return;
    const float* bp; int o, stride;
    if (t < 1024)      { bp = b0; o = t;        stride = 1024; }
    else if (t < 2048) { bp = b1; o = t - 1024; stride = 1024; }
    else               { bp = b2; o = t - 2048; stride = 512;  }
    float acc = 0.f;
    #pragma unroll
    for (int e = 0; e < 8; ++e) acc += wn[e] * bp[e * stride + o];
    bm[t] = acc * inv;
}

// ------------- GEMM + bias + PReLU (R5, byte-identical — proven tied-best) -------------
// A [M,K] bf16 row-major, Bt [N,K] bf16 (B^T), out [M,N].
// 128x128 tile, BK=64, 256 thr = 4 waves in 2x2, each wave 64x64 = 4x4 MFMA 16x16x32.
template <bool OUT_F32, int NN_LOG2>
__global__ __launch_bounds__(256) void gemm_bias_prelu(
    const u16* __restrict__ A, const u16* __restrict__ Bt,
    const float* __restrict__ bias, const float* __restrict__ alpha,
    void* __restrict__ outp, int M, int N, int K) {
    __shared__ __align__(16) u16 As[128 * 64];   // 16 KB
    __shared__ __align__(16) u16 Bs[128 * 64];   // 16 KB
    const int tid = threadIdx.x;

    const int xcd   = blockIdx.x & 7;
    const int inner = blockIdx.x >> 3;
    const int bn    = inner & ((1 << NN_LOG2) - 1);
    const int bmv   = xcd * 8 + (inner >> NN_LOG2);

    const int r0 = tid >> 3;
    const int p  = tid & 7;
    const int c  = p ^ (r0 & 7);       // XOR swizzle on GLOBAL source (LDS lane-contiguous)
    const u16* Ag = A  + (size_t)(bmv * 128 + r0) * K + c * 8;
    const u16* Bg = Bt + (size_t)(bn * 128 + r0) * K + c * 8;
    u16* Al = As + tid * 8;
    u16* Bl = Bs + tid * 8;

    const int lane = tid & 63, w = tid >> 6;
    const int wm = (w >> 1) * 64, wn = (w & 1) * 64;
    const int l16 = lane & 15, quad = lane >> 4;
    const int xr = l16 & 7;
    const short8* As8 = (const short8*)As;
    const short8* Bs8 = (const short8*)Bs;

    float4v acc[4][4] = {};

    const int nk = K >> 6;
    for (int kt = 0; kt < nk; ++kt) {
        #pragma unroll
        for (int it = 0; it < 4; ++it) {
            gload16(Ag + (size_t)(it * 32) * K, Al + it * 2048);
            gload16(Bg + (size_t)(it * 32) * K, Bl + it * 2048);
        }
        __syncthreads();
        #pragma unroll
        for (int kk = 0; kk < 2; ++kk) {
            const int cb = kk * 4;
            short8 af[4], bf[4];
            #pragma unroll
            for (int mi = 0; mi < 4; ++mi)
                af[mi] = As8[(wm + mi * 16 + l16) * 8 + ((cb + quad) ^ xr)];
            #pragma unroll
            for (int ni = 0; ni < 4; ++ni)
                bf[ni] = Bs8[(wn + ni * 16 + l16) * 8 + ((cb + quad) ^ xr)];
            #pragma unroll
            for (int mi = 0; mi < 4; ++mi)
                #pragma unroll
                for (int ni = 0; ni < 4; ++ni)
                    acc[mi][ni] = __builtin_amdgcn_mfma_f32_16x16x32_bf16(
                        af[mi], bf[ni], acc[mi][ni], 0, 0, 0);
        }
        if (kt + 1 < nk) __syncthreads();
        Ag += 64; Bg += 64;
    }

    // epilogue: C/D layout col=lane&15, row=quad*4+reg  [m89/m91; R1-R6 proven]
    const int cbase = bn * 128 + wn + l16;
    float bv[4], av[4];
    #pragma unroll
    for (int ni = 0; ni < 4; ++ni) { bv[ni] = bias[cbase + ni * 16]; av[ni] = alpha[cbase + ni * 16]; }
    const int rbase = bmv * 128 + wm + quad * 4;
    #pragma unroll
    for (int mi = 0; mi < 4; ++mi) {
        #pragma unroll
        for (int reg = 0; reg < 4; ++reg) {
            int r = rbase + mi * 16 + reg;
            #pragma unroll
            for (int ni = 0; ni < 4; ++ni) {
                float v = acc[mi][ni][reg] + bv[ni];
                v = v >= 0.f ? v : av[ni] * v;
                size_t idx = (size_t)r * N + cbase + ni * 16;
                if (OUT_F32) ((float*)outp)[idx] = v;
                else         ((u16*)outp)[idx] = f2bf(v);
            }
        }
    }
}

extern "C" void kernel_launch(void* const* d_in, const int* in_sizes, int n_in,
                              void* d_out, int out_size, void* d_ws, size_t ws_size,
                              hipStream_t stream) {
    const float* x   = (const float*)d_in[0];
    const float* wts = (const float*)d_in[1];
    const float* W0  = (const float*)d_in[2];
    const float* b0  = (const float*)d_in[3];
    const float* a0  = (const float*)d_in[4];
    const float* W1  = (const float*)d_in[5];
    const float* b1  = (const float*)d_in[6];
    const float* a1  = (const float*)d_in[7];
    const float* W2  = (const float*)d_in[8];
    const float* b2  = (const float*)d_in[9];
    const float* a2  = (const float*)d_in[10];
    float* out = (float*)d_out;

    char* ws = (char*)d_ws;
    u16*   xbf  = (u16*)ws;  ws += (size_t)8192 * 512 * 2;
    u16*   act1 = (u16*)ws;  ws += (size_t)8192 * 1024 * 2;
    u16*   act2 = (u16*)ws;  ws += (size_t)8192 * 1024 * 2;
    u16*   W0t  = (u16*)ws;  ws += (size_t)1024 * 512 * 2;
    u16*   W1t  = (u16*)ws;  ws += (size_t)1024 * 1024 * 2;
    u16*   W2t  = (u16*)ws;  ws += (size_t)512 * 1024 * 2;
    float* bm   = (float*)ws;  // 2560 floats

    // prep: 4096 cvt + 512 merge + 10 bias = 4618 blocks
    prep_fused<<<4618, 256, 0, stream>>>(x, xbf, wts, W0, W1, W2, W0t, W1t, W2t,
                                         b0, b1, b2, bm);

    // GEMM layers (R5 grids): xcd = bid&7 -> M-slab; L0/L1 512 blocks; L2 256.
    gemm_bias_prelu<false, 3><<<512, 256, 0, stream>>>(xbf,  W0t, bm,        a0, act1, 8192, 1024, 512);
    gemm_bias_prelu<false, 3><<<512, 256, 0, stream>>>(act1, W1t, bm + 1024, a1, act2, 8192, 1024, 1024);
    gemm_bias_prelu<true,  2><<<256, 256, 0, stream>>>(act2, W2t, bm + 2048, a2, out,  8192, 512, 1024);
}